// Round 14
// baseline (529.696 us; speedup 1.0000x reference)
//
#include <hip/hip_runtime.h>
#include <math.h>

#define T_STEPS 120
#define BATCH   1024

typedef __attribute__((ext_vector_type(8))) short bf16x8;
typedef __attribute__((ext_vector_type(4))) float f32x4;
typedef unsigned short u16;

// split f into hi (truncated bf16) + lo (RNE bf16 of remainder); f ~= hi+lo
__device__ __forceinline__ unsigned split2(float f) {
    union { float f; unsigned u; } a; a.f = f;
    unsigned hi = a.u >> 16;
    union { float f; unsigned u; } h; h.u = a.u & 0xFFFF0000u;
    union { float f; unsigned u; } b; b.f = f - h.f;
    unsigned rr = b.u + 0x7FFFu + ((b.u >> 16) & 1);
    return (hi << 16) | (rr >> 16);
}

// round-to-nearest-even bf16 (static weights / feedforward activations)
__device__ __forceinline__ short bf16rne(float f) {
    union { float f; unsigned u; } a; a.f = f;
    unsigned r = a.u + 0x7FFFu + ((a.u >> 16) & 1);
    return (short)(r >> 16);
}

__device__ __forceinline__ float fast_sigmoid(float x) {
    float e = __expf(-x);
    return __builtin_amdgcn_rcpf(1.f + e);
}

// LDS-visibility-only barrier: does NOT drain vmcnt, so global prefetch
// loads and h stores stay in flight across the step boundary.
__device__ __forceinline__ void block_sync_lds() {
    asm volatile("s_waitcnt lgkmcnt(0)" ::: "memory");
    __builtin_amdgcn_sched_barrier(0);
    __builtin_amdgcn_s_barrier();
    __builtin_amdgcn_sched_barrier(0);
}

// ---------------------------------------------------------------------------
// x (B,T,132) fp32 -> bf16 hi plane (B,T,144), zero-padded.
// ---------------------------------------------------------------------------
__global__ __launch_bounds__(256)
void xconv(const float* __restrict__ x, u16* __restrict__ xhi)
{
    int idx = blockIdx.x * 256 + threadIdx.x;
    int k   = idx % 144;
    int bt  = idx / 144;
    float f = (k < 132) ? x[(size_t)bt * 132 + k] : 0.f;
    xhi[idx] = (u16)(unsigned short)bf16rne(f);
}

// ---------------------------------------------------------------------------
// Unified combined-wave fused LSTM layer (L2's proven structure).
// 512 threads = 8 identical waves, each owning 16 units x 16 batch rows.
//   wave wid: unit group ug = wid % (U/16), batch half bh = wid / (U/16).
//   U=128: 8 unit groups, 1 batch half (NBT=16, grid 64).
//   U=64:  4 unit groups, 2 batch halves (NBT=32, grid 32).
// Per step: z = b + x_t @ W (W in LDS, x single-bf16 from global, prefetch
// 1 ahead) + h @ U (U in regs, h hi/lo from LDS planes, double-buffered);
// gates in-lane; one lgkm-only barrier per step. No spill (<=128 VGPR).
// ---------------------------------------------------------------------------
template<int U, int NBT, int KXD, int KTX, int KTAIL, bool LAST_ONLY>
__global__ __launch_bounds__(512, 1)
void lstm_comb(const u16* __restrict__ xhi,
               const float* __restrict__ W, int KIN,
               const float* __restrict__ Uw, const float* __restrict__ bias,
               u16* __restrict__ hhi, float* __restrict__ hlast)
{
    constexpr int NZ  = 4 * U;
    constexpr int KTH = U / 32;
    constexpr int KXP = KTX * 32;           // padded W rows
    constexpr int HPLANE = NBT * U;         // u16 per h plane per buffer
    constexpr int UG  = U / 16;
    static_assert(UG * (NBT / 16) == 8, "8 waves");

    __shared__ u16 hsh[4 * HPLANE];         // [buf][hi/lo][NBT*U]
    __shared__ u16 Wl[KXP * NZ];            // tiled [k>>3][n][k&7]

    const int tid  = threadIdx.x;
    const int lane = tid & 63;
    const int wid  = tid >> 6;
    const int ln   = lane & 15;
    const int lq   = lane >> 4;
    const int ug   = wid % UG;
    const int bh   = wid / UG;
    const int unit = ug * 16 + ln;
    const int bb   = bh * 16;               // batch base within block
    const int b0   = blockIdx.x * NBT;

    // ---- stage W into LDS (one-time, coalesced, zero-padded) ----
    for (int idx = tid; idx < KXP * NZ; idx += 512) {
        int k = idx / NZ, n = idx % NZ;
        float f = (k < KIN) ? W[(size_t)k * NZ + n] : 0.f;
        Wl[((k >> 3) * NZ + n) * 8 + (k & 7)] = (u16)bf16rne(f);
    }

    // ---- U into registers (single RNE bf16) ----
    bf16x8 bwu[4][KTH];
#pragma unroll
    for (int p = 0; p < 4; ++p)
#pragma unroll
        for (int kt = 0; kt < KTH; ++kt)
#pragma unroll
            for (int e = 0; e < 8; ++e) {
                int k = kt * 32 + lq * 8 + e;
                bwu[p][kt][e] = bf16rne(Uw[(size_t)k * NZ + p * U + unit]);
            }
    float breg[4];
#pragma unroll
    for (int p = 0; p < 4; ++p) breg[p] = bias[p * U + unit];

    // ---- h state init: zero both planes of buf0; c = 0 ----
    u16* hw0 = hsh + ((unit >> 3) * NBT + bb + lq * 4) * 8 + (unit & 7);
    u16* hw1 = hw0 + 2 * HPLANE;
    float creg[4];
#pragma unroll
    for (int r = 0; r < 4; ++r) {
        creg[r] = 0.f;
        hw0[r * 8] = 0;
        hw0[HPLANE + r * 8] = 0;
    }

    const u16* hrd[2][KTH];
#pragma unroll
    for (int b = 0; b < 2; ++b)
#pragma unroll
        for (int kt = 0; kt < KTH; ++kt)
            hrd[b][kt] = hsh + b * 2 * HPLANE + ((kt * 4 + lq) * NBT + bb + ln) * 8;

    // W-frag base: frag(kt,p) at wb + (kt*4*NZ + p*U)*8 elements
    const u16* wb = Wl + ((size_t)lq * NZ + unit) * 8;

    // ---- x pointer + first prefetch (zero frags beyond data width) ----
    const u16* pxh = xhi + ((size_t)(b0 + bb + ln) * T_STEPS) * KXD + lq * 8;
    bf16x8 xfh[KTX] = {};
#pragma unroll
    for (int kt = 0; kt < KTX; ++kt)
        if (kt < KTX - 1 || lq < KTAIL)
            xfh[kt] = *reinterpret_cast<const bf16x8*>(pxh + kt * 32);

    size_t ho = ((size_t)(b0 + bb + lq * 4) * T_STEPS) * U + unit;

    block_sync_lds();

#define CSTEP(CUR, OTH, tc)                                                     \
    {                                                                           \
        f32x4 acc[4] = {};                                                      \
        _Pragma("unroll")                                                       \
        for (int kt = 0; kt < KTH; ++kt) {                                      \
            bf16x8 ahh = *reinterpret_cast<const bf16x8*>(hrd[CUR][kt]);        \
            bf16x8 ahl = *reinterpret_cast<const bf16x8*>(hrd[CUR][kt] + HPLANE); \
            _Pragma("unroll")                                                   \
            for (int p = 0; p < 4; ++p) {                                       \
                acc[p] = __builtin_amdgcn_mfma_f32_16x16x32_bf16(ahh, bwu[p][kt], acc[p], 0, 0, 0); \
                acc[p] = __builtin_amdgcn_mfma_f32_16x16x32_bf16(ahl, bwu[p][kt], acc[p], 0, 0, 0); \
            }                                                                   \
        }                                                                       \
        _Pragma("unroll")                                                       \
        for (int kt = 0; kt < KTX; ++kt)                                        \
        _Pragma("unroll")                                                       \
        for (int p = 0; p < 4; ++p) {                                           \
            bf16x8 wf = *reinterpret_cast<const bf16x8*>(wb + ((size_t)kt * 4 * NZ + p * U) * 8); \
            acc[p] = __builtin_amdgcn_mfma_f32_16x16x32_bf16(xfh[kt], wf, acc[p], 0, 0, 0); \
        }                                                                       \
        if ((tc) + 1 < T_STEPS) {                                               \
            pxh += KXD;                                                         \
            _Pragma("unroll")                                                   \
            for (int kt = 0; kt < KTX; ++kt)                                    \
                if (kt < KTX - 1 || lq < KTAIL)                                 \
                    xfh[kt] = *reinterpret_cast<const bf16x8*>(pxh + kt * 32);  \
        }                                                                       \
        _Pragma("unroll")                                                       \
        for (int r = 0; r < 4; ++r) {                                           \
            float si = fast_sigmoid(acc[0][r] + breg[0]);                       \
            float sf = fast_sigmoid(acc[1][r] + breg[1]);                       \
            float gg = fmaxf(acc[2][r] + breg[2], 0.f);                         \
            float so = fast_sigmoid(acc[3][r] + breg[3]);                       \
            float c  = sf * creg[r] + si * gg;                                  \
            creg[r] = c;                                                        \
            float h = so * fmaxf(c, 0.f);                                       \
            unsigned s = split2(h);                                             \
            u16* hw = (OTH) ? hw1 : hw0;                                        \
            hw[r * 8] = (u16)(s >> 16);                                         \
            hw[HPLANE + r * 8] = (u16)s;                                        \
            if constexpr (!LAST_ONLY) {                                         \
                hhi[ho + (size_t)r * (T_STEPS * U) + (size_t)(tc) * U] = (u16)(s >> 16); \
            } else {                                                            \
                if ((tc) == T_STEPS - 1)                                        \
                    hlast[(size_t)(b0 + bb + lq * 4 + r) * U + unit] = h;       \
            }                                                                   \
        }                                                                       \
        block_sync_lds();                                                       \
    }

    for (int t = 0; t < T_STEPS; t += 2) {
        CSTEP(0, 1, t)
        CSTEP(1, 0, t + 1)
    }
#undef CSTEP
}

// Dense head: one wave per batch row. 64 ->relu-> 64 ->relu-> 32 -> 101 -> softmax
__global__ __launch_bounds__(256)
void dense_head(const float* __restrict__ h3,    // (B,64)
                const float* __restrict__ Wd1, const float* __restrict__ bd1,
                const float* __restrict__ Wd2, const float* __restrict__ bd2,
                const float* __restrict__ Wd3, const float* __restrict__ bd3,
                float* __restrict__ out)         // (B,101)
{
    __shared__ float s1[4][64];
    __shared__ float s2[4][32];
    const int w    = threadIdx.x >> 6;
    const int lane = threadIdx.x & 63;
    const int row  = blockIdx.x * 4 + w;

    float hval = h3[(size_t)row * 64 + lane];
    float a = bd1[lane];
#pragma unroll
    for (int k = 0; k < 64; ++k) {
        float hk = __shfl(hval, k, 64);
        a = fmaf(hk, Wd1[k * 64 + lane], a);
    }
    s1[w][lane] = fmaxf(a, 0.f);
    __syncthreads();

    if (lane < 32) {
        float a2 = bd2[lane];
#pragma unroll
        for (int k = 0; k < 64; ++k) a2 = fmaf(s1[w][k], Wd2[k * 32 + lane], a2);
        s2[w][lane] = fmaxf(a2, 0.f);
    }
    __syncthreads();

    float a0 = bd3[lane];
#pragma unroll
    for (int k = 0; k < 32; ++k) a0 = fmaf(s2[w][k], Wd3[k * 101 + lane], a0);
    float a1 = -INFINITY;
    if (lane < 37) {
        a1 = bd3[64 + lane];
#pragma unroll
        for (int k = 0; k < 32; ++k) a1 = fmaf(s2[w][k], Wd3[k * 101 + 64 + lane], a1);
    }

    float m = fmaxf(a0, a1);
#pragma unroll
    for (int off = 32; off > 0; off >>= 1) m = fmaxf(m, __shfl_xor(m, off, 64));
    float e0 = expf(a0 - m);
    float e1 = (lane < 37) ? expf(a1 - m) : 0.f;
    float s = e0 + e1;
#pragma unroll
    for (int off = 32; off > 0; off >>= 1) s += __shfl_xor(s, off, 64);

    out[(size_t)row * 101 + lane] = e0 / s;
    if (lane < 37) out[(size_t)row * 101 + 64 + lane] = e1 / s;
}

extern "C" void kernel_launch(void* const* d_in, const int* in_sizes, int n_in,
                              void* d_out, int out_size, void* d_ws, size_t ws_size,
                              hipStream_t stream) {
    const float* x   = (const float*)d_in[0];
    const float* W1  = (const float*)d_in[1];
    const float* U1  = (const float*)d_in[2];
    const float* b1  = (const float*)d_in[3];
    const float* W2  = (const float*)d_in[4];
    const float* U2  = (const float*)d_in[5];
    const float* b2  = (const float*)d_in[6];
    const float* W3  = (const float*)d_in[7];
    const float* U3  = (const float*)d_in[8];
    const float* b3  = (const float*)d_in[9];
    const float* Wd1 = (const float*)d_in[10];
    const float* bd1 = (const float*)d_in[11];
    const float* Wd2 = (const float*)d_in[12];
    const float* bd2 = (const float*)d_in[13];
    const float* Wd3 = (const float*)d_in[14];
    const float* bd3 = (const float*)d_in[15];

    // workspace (u16 units). x plane aliased by h2 plane after L1 consumes x.
    u16* ws16 = (u16*)d_ws;
    u16* xhi  = ws16;                         // 1024*120*144 = 17,694,720
    u16* h2hi = ws16;                         // alias (x dead after L1)
    u16* h1hi = ws16 + 17694720;              // 1024*120*64 = 7,864,320
    float* h3 = (float*)(ws16 + 25559040);    // 1024*64 fp32

    // 1) pad/round input x -> bf16 plane
    xconv<<<(BATCH * T_STEPS * 144) / 256, 256, 0, stream>>>(x, xhi);
    // 2) layer 1: U=64, NBT=32 (grid 32), Kx 144 (5 tiles, tail lq<2)
    lstm_comb<64, 32, 144, 5, 2, false><<<32, 512, 0, stream>>>(
        xhi, W1, 132, U1, b1, h1hi, nullptr);
    // 3) layer 2: U=128, NBT=16 (grid 64), Kx 64 (2 tiles)
    lstm_comb<128, 16, 64, 2, 4, false><<<64, 512, 0, stream>>>(
        h1hi, W2, 64, U2, b2, h2hi, nullptr);
    // 4) layer 3: U=64, NBT=32 (grid 32), Kx 128 (4 tiles), last h only
    lstm_comb<64, 32, 128, 4, 4, true><<<32, 512, 0, stream>>>(
        h2hi, W3, 128, U3, b3, nullptr, h3);
    // 5) dense head + softmax
    dense_head<<<BATCH / 4, 256, 0, stream>>>(h3, Wd1, bd1, Wd2, bd2, Wd3, bd3,
                                              (float*)d_out);
}

// Round 15
// 495.838 us; speedup vs baseline: 1.0683x; 1.0683x over previous
//
#include <hip/hip_runtime.h>
#include <math.h>

#define T_STEPS 120
#define BATCH   1024
#define NBK     64        // batch groups of 16

typedef __attribute__((ext_vector_type(8))) short bf16x8;
typedef __attribute__((ext_vector_type(4))) float f32x4;
typedef __attribute__((ext_vector_type(4))) unsigned short us4;
typedef unsigned short u16;

// split f into hi (truncated bf16) + lo (RNE bf16 of remainder); f ~= hi+lo
__device__ __forceinline__ unsigned split2(float f) {
    union { float f; unsigned u; } a; a.f = f;
    unsigned hi = a.u >> 16;
    union { float f; unsigned u; } h; h.u = a.u & 0xFFFF0000u;
    union { float f; unsigned u; } b; b.f = f - h.f;
    unsigned rr = b.u + 0x7FFFu + ((b.u >> 16) & 1);
    return (hi << 16) | (rr >> 16);
}

// round-to-nearest-even bf16 (static weights / feedforward activations)
__device__ __forceinline__ short bf16rne(float f) {
    union { float f; unsigned u; } a; a.f = f;
    unsigned r = a.u + 0x7FFFu + ((a.u >> 16) & 1);
    return (short)(r >> 16);
}

__device__ __forceinline__ float fast_sigmoid(float x) {
    float e = __expf(-x);
    return __builtin_amdgcn_rcpf(1.f + e);
}

// LDS-visibility-only barrier: does NOT drain vmcnt, so global prefetch
// loads and h stores stay in flight across the step boundary.
__device__ __forceinline__ void block_sync_lds() {
    asm volatile("s_waitcnt lgkmcnt(0)" ::: "memory");
    __builtin_amdgcn_sched_barrier(0);
    __builtin_amdgcn_s_barrier();
    __builtin_amdgcn_sched_barrier(0);
}

// ---------------------------------------------------------------------------
// x (B,T,132) fp32 -> frag-major bf16 XF[t][bk 64][kt 5][lane 64][e 8],
// where b = bk*16 + (lane&15), k = kt*32 + (lane>>4)*8 + e (0 for k>=132).
// Each thread produces one 8-elem run (16B contiguous write).
// ---------------------------------------------------------------------------
__global__ __launch_bounds__(256)
void xconv(const float* __restrict__ x, u16* __restrict__ xf)
{
    int tid  = blockIdx.x * 256 + threadIdx.x;   // 120*64*5*64 threads
    int lane = tid & 63;
    int rest = tid >> 6;                          // (t*64+bk)*5+kt
    int kt   = rest % 5;
    int tbk  = rest / 5;
    int bk   = tbk & 63;
    int t    = tbk >> 6;
    int ln   = lane & 15, lq = lane >> 4;
    int b    = bk * 16 + ln;
    int k0   = kt * 32 + lq * 8;
    const float* src = &x[((size_t)b * T_STEPS + t) * 132];
    u16 out[8];
#pragma unroll
    for (int e = 0; e < 8; ++e) {
        int k = k0 + e;
        out[e] = (u16)bf16rne((k < 132) ? src[k] : 0.f);
    }
    us4 o0, o1;
    o0.x = out[0]; o0.y = out[1]; o0.z = out[2]; o0.w = out[3];
    o1.x = out[4]; o1.y = out[5]; o1.z = out[6]; o1.w = out[7];
    *reinterpret_cast<us4*>(&xf[(size_t)tid * 8])     = o0;
    *reinterpret_cast<us4*>(&xf[(size_t)tid * 8 + 4]) = o1;
}

// ---------------------------------------------------------------------------
// Combined-wave fused LSTM layer, frag-major activation I/O.
// 512 threads = 8 identical waves: ug = wid % (U/16), batch half bh = wid/(U/16).
// x input XF[t][bk][kt<KTXI][lane][8]: ONE coalesced dwordx4 load per kt per
// step, identical across the ug-waves of a batch half (L1-cache broadcast).
// h output written frag-major for the next layer (KTXO tiles) or fp32 hlast.
// W in LDS (tiled [k>>3][n][8]), U register-resident, h hi/lo LDS planes.
// ---------------------------------------------------------------------------
template<int U, int NBT, int KTXI, int KTXO, bool LAST_ONLY>
__global__ __launch_bounds__(512, 1)
void lstm_comb(const u16* __restrict__ xf,
               const float* __restrict__ W, int KIN,
               const float* __restrict__ Uw, const float* __restrict__ bias,
               u16* __restrict__ hf, float* __restrict__ hlast)
{
    constexpr int NZ  = 4 * U;
    constexpr int KTH = U / 32;
    constexpr int KXP = KTXI * 32;
    constexpr int HPLANE = NBT * U;
    constexpr int UG  = U / 16;
    constexpr size_t XSTRIDE = (size_t)NBK * KTXI * 512;   // u16 per t
    constexpr size_t OSTRIDE = (size_t)NBK * KTXO * 512;
    static_assert(UG * (NBT / 16) == 8, "8 waves");

    __shared__ u16 hsh[4 * HPLANE];
    __shared__ u16 Wl[KXP * NZ];

    const int tid  = threadIdx.x;
    const int lane = tid & 63;
    const int wid  = tid >> 6;
    const int ln   = lane & 15;
    const int lq   = lane >> 4;
    const int ug   = wid % UG;
    const int bh   = wid / UG;
    const int unit = ug * 16 + ln;
    const int bb   = bh * 16;
    const int b0   = blockIdx.x * NBT;
    const int bkw  = (b0 + bb) >> 4;        // batch-16 group of this wave

    // ---- stage W into LDS (one-time, coalesced, zero-padded) ----
    for (int idx = tid; idx < KXP * NZ; idx += 512) {
        int k = idx / NZ, n = idx % NZ;
        float f = (k < KIN) ? W[(size_t)k * NZ + n] : 0.f;
        Wl[((k >> 3) * NZ + n) * 8 + (k & 7)] = (u16)bf16rne(f);
    }

    // ---- U into registers (single RNE bf16) ----
    bf16x8 bwu[4][KTH];
#pragma unroll
    for (int p = 0; p < 4; ++p)
#pragma unroll
        for (int kt = 0; kt < KTH; ++kt)
#pragma unroll
            for (int e = 0; e < 8; ++e) {
                int k = kt * 32 + lq * 8 + e;
                bwu[p][kt][e] = bf16rne(Uw[(size_t)k * NZ + p * U + unit]);
            }
    float breg[4];
#pragma unroll
    for (int p = 0; p < 4; ++p) breg[p] = bias[p * U + unit];

    // ---- h state init: zero both planes of buf0; c = 0 ----
    u16* hw0 = hsh + ((unit >> 3) * NBT + bb + lq * 4) * 8 + (unit & 7);
    u16* hw1 = hw0 + 2 * HPLANE;
    float creg[4];
#pragma unroll
    for (int r = 0; r < 4; ++r) {
        creg[r] = 0.f;
        hw0[r * 8] = 0;
        hw0[HPLANE + r * 8] = 0;
    }

    const u16* hrd[2][KTH];
#pragma unroll
    for (int b = 0; b < 2; ++b)
#pragma unroll
        for (int kt = 0; kt < KTH; ++kt)
            hrd[b][kt] = hsh + b * 2 * HPLANE + ((kt * 4 + lq) * NBT + bb + ln) * 8;

    // W-frag base: frag(kt,p) at wb + (kt*4*NZ + p*U)*8 elements
    const u16* wb = Wl + ((size_t)lq * NZ + unit) * 8;

    // ---- x frag pointer + first prefetch (coalesced: lane*8 contiguous) ----
    const u16* pxf = xf + ((size_t)bkw * KTXI) * 512 + lane * 8;
    bf16x8 xfh[KTXI];
#pragma unroll
    for (int kt = 0; kt < KTXI; ++kt)
        xfh[kt] = *reinterpret_cast<const bf16x8*>(pxf + kt * 512);

    // ---- output base (frag layout for next layer) ----
    u16* hfo = nullptr;
    if constexpr (!LAST_ONLY) {
        int kto = unit >> 5;
        int lqp = (unit >> 3) & 3;
        int ep  = unit & 7;
        hfo = hf + (((size_t)bkw * KTXO + kto) * 64 + lqp * 16 + lq * 4) * 8 + ep;
    }

    block_sync_lds();

#define CSTEP(CUR, OTH, tc)                                                     \
    {                                                                           \
        f32x4 acc[4] = {};                                                      \
        _Pragma("unroll")                                                       \
        for (int kt = 0; kt < KTH; ++kt) {                                      \
            bf16x8 ahh = *reinterpret_cast<const bf16x8*>(hrd[CUR][kt]);        \
            bf16x8 ahl = *reinterpret_cast<const bf16x8*>(hrd[CUR][kt] + HPLANE); \
            _Pragma("unroll")                                                   \
            for (int p = 0; p < 4; ++p) {                                       \
                acc[p] = __builtin_amdgcn_mfma_f32_16x16x32_bf16(ahh, bwu[p][kt], acc[p], 0, 0, 0); \
                acc[p] = __builtin_amdgcn_mfma_f32_16x16x32_bf16(ahl, bwu[p][kt], acc[p], 0, 0, 0); \
            }                                                                   \
        }                                                                       \
        _Pragma("unroll")                                                       \
        for (int kt = 0; kt < KTXI; ++kt)                                       \
        _Pragma("unroll")                                                       \
        for (int p = 0; p < 4; ++p) {                                           \
            bf16x8 wf = *reinterpret_cast<const bf16x8*>(wb + ((size_t)kt * 4 * NZ + p * U) * 8); \
            acc[p] = __builtin_amdgcn_mfma_f32_16x16x32_bf16(xfh[kt], wf, acc[p], 0, 0, 0); \
        }                                                                       \
        if ((tc) + 1 < T_STEPS) {                                               \
            pxf += XSTRIDE;                                                     \
            _Pragma("unroll")                                                   \
            for (int kt = 0; kt < KTXI; ++kt)                                   \
                xfh[kt] = *reinterpret_cast<const bf16x8*>(pxf + kt * 512);     \
        }                                                                       \
        _Pragma("unroll")                                                       \
        for (int r = 0; r < 4; ++r) {                                           \
            float si = fast_sigmoid(acc[0][r] + breg[0]);                       \
            float sf = fast_sigmoid(acc[1][r] + breg[1]);                       \
            float gg = fmaxf(acc[2][r] + breg[2], 0.f);                         \
            float so = fast_sigmoid(acc[3][r] + breg[3]);                       \
            float c  = sf * creg[r] + si * gg;                                  \
            creg[r] = c;                                                        \
            float h = so * fmaxf(c, 0.f);                                       \
            unsigned s = split2(h);                                             \
            u16* hw = (OTH) ? hw1 : hw0;                                        \
            hw[r * 8] = (u16)(s >> 16);                                         \
            hw[HPLANE + r * 8] = (u16)s;                                        \
            if constexpr (!LAST_ONLY) {                                         \
                hfo[(size_t)(tc) * OSTRIDE + r * 8] = (u16)(s >> 16);           \
            } else {                                                            \
                if ((tc) == T_STEPS - 1)                                        \
                    hlast[(size_t)(b0 + bb + lq * 4 + r) * U + unit] = h;       \
            }                                                                   \
        }                                                                       \
        block_sync_lds();                                                       \
    }

    for (int t = 0; t < T_STEPS; t += 2) {
        CSTEP(0, 1, t)
        CSTEP(1, 0, t + 1)
    }
#undef CSTEP
}

// Dense head: one wave per batch row. 64 ->relu-> 64 ->relu-> 32 -> 101 -> softmax
__global__ __launch_bounds__(256)
void dense_head(const float* __restrict__ h3,    // (B,64)
                const float* __restrict__ Wd1, const float* __restrict__ bd1,
                const float* __restrict__ Wd2, const float* __restrict__ bd2,
                const float* __restrict__ Wd3, const float* __restrict__ bd3,
                float* __restrict__ out)         // (B,101)
{
    __shared__ float s1[4][64];
    __shared__ float s2[4][32];
    const int w    = threadIdx.x >> 6;
    const int lane = threadIdx.x & 63;
    const int row  = blockIdx.x * 4 + w;

    float hval = h3[(size_t)row * 64 + lane];
    float a = bd1[lane];
#pragma unroll
    for (int k = 0; k < 64; ++k) {
        float hk = __shfl(hval, k, 64);
        a = fmaf(hk, Wd1[k * 64 + lane], a);
    }
    s1[w][lane] = fmaxf(a, 0.f);
    __syncthreads();

    if (lane < 32) {
        float a2 = bd2[lane];
#pragma unroll
        for (int k = 0; k < 64; ++k) a2 = fmaf(s1[w][k], Wd2[k * 32 + lane], a2);
        s2[w][lane] = fmaxf(a2, 0.f);
    }
    __syncthreads();

    float a0 = bd3[lane];
#pragma unroll
    for (int k = 0; k < 32; ++k) a0 = fmaf(s2[w][k], Wd3[k * 101 + lane], a0);
    float a1 = -INFINITY;
    if (lane < 37) {
        a1 = bd3[64 + lane];
#pragma unroll
        for (int k = 0; k < 32; ++k) a1 = fmaf(s2[w][k], Wd3[k * 101 + 64 + lane], a1);
    }

    float m = fmaxf(a0, a1);
#pragma unroll
    for (int off = 32; off > 0; off >>= 1) m = fmaxf(m, __shfl_xor(m, off, 64));
    float e0 = expf(a0 - m);
    float e1 = (lane < 37) ? expf(a1 - m) : 0.f;
    float s = e0 + e1;
#pragma unroll
    for (int off = 32; off > 0; off >>= 1) s += __shfl_xor(s, off, 64);

    out[(size_t)row * 101 + lane] = e0 / s;
    if (lane < 37) out[(size_t)row * 101 + 64 + lane] = e1 / s;
}

extern "C" void kernel_launch(void* const* d_in, const int* in_sizes, int n_in,
                              void* d_out, int out_size, void* d_ws, size_t ws_size,
                              hipStream_t stream) {
    const float* x   = (const float*)d_in[0];
    const float* W1  = (const float*)d_in[1];
    const float* U1  = (const float*)d_in[2];
    const float* b1  = (const float*)d_in[3];
    const float* W2  = (const float*)d_in[4];
    const float* U2  = (const float*)d_in[5];
    const float* b2  = (const float*)d_in[6];
    const float* W3  = (const float*)d_in[7];
    const float* U3  = (const float*)d_in[8];
    const float* b3  = (const float*)d_in[9];
    const float* Wd1 = (const float*)d_in[10];
    const float* bd1 = (const float*)d_in[11];
    const float* Wd2 = (const float*)d_in[12];
    const float* bd2 = (const float*)d_in[13];
    const float* Wd3 = (const float*)d_in[14];
    const float* bd3 = (const float*)d_in[15];

    // workspace (u16 units), frag-major activation buffers
    u16* ws16 = (u16*)d_ws;
    u16* xfb  = ws16;                         // 120*64*5*512 = 19,660,800
    u16* h1f  = ws16 + 19660800;              // 120*64*2*512 = 7,864,320
    u16* h2f  = h1f + 7864320;                // 120*64*4*512 = 15,728,640
    float* h3 = (float*)(ws16 + 43253760);    // 1024*64 fp32

    // 1) x -> frag-major bf16 (zero-padded to 160 k)
    xconv<<<(T_STEPS * NBK * 5 * 64) / 256, 256, 0, stream>>>(x, xfb);
    // 2) layer 1: U=64, NBT=32 (grid 32), x 5 tiles in, 2 tiles out
    lstm_comb<64, 32, 5, 2, false><<<32, 512, 0, stream>>>(
        xfb, W1, 132, U1, b1, h1f, nullptr);
    // 3) layer 2: U=128, NBT=16 (grid 64), 2 tiles in, 4 tiles out
    lstm_comb<128, 16, 2, 4, false><<<64, 512, 0, stream>>>(
        h1f, W2, 64, U2, b2, h2f, nullptr);
    // 4) layer 3: U=64, NBT=32 (grid 32), 4 tiles in, last h only
    lstm_comb<64, 32, 4, 1, true><<<32, 512, 0, stream>>>(
        h2f, W3, 128, U3, b3, nullptr, h3);
    // 5) dense head + softmax
    dense_head<<<BATCH / 4, 256, 0, stream>>>(h3, Wd1, bd1, Wd2, bd2, Wd3, bd3,
                                              (float*)d_out);
}